// Round 14
// baseline (201.758 us; speedup 1.0000x reference)
//
#include <hip/hip_runtime.h>
#include <math.h>

#define R_NODES 1152
#define DIGITS 10
#define OUT_CH 16
#define IN_CH 8
#define BATCH 256
#define COLS 160            // DIGITS*OUT_CH
#define W_PER_R 1280        // DIGITS*OUT_CH*IN_CH
#define NSPLIT 192          // K-split: 6 r-rows per block
#define RPS 6               // rows per split
#define YB_S 8              // k_s batch blocks (32 b each)  [r14: was 4]
#define YBLK 8              // k_a batch blocks (32 b each)
#define UPAD 51             // u-LDS batch stride: bs*102 mod 32 = bs*6 -> conflict-free
#define AB_STRIDE (YBLK * R_NODES * DIGITS)   // 92160 floats per ab iteration-buffer

// ---------- s partials: o-lane layout, W global->regs (L1), u via LDS ----------
// grid (192, 8) = 1536 blocks = 6 blocks/CU. 256 thr = 16 o-lanes x 16 bs;
// thread owns batches bs*2+jj (jj=0..1) and cols d*16+o (d=0..9).
// r13 lesson: store pattern was NOT the cost (transpose regressed). r12's
// structure kept, batch-split doubled: every k_s since r5 ran at 3 blocks/CU
// (768 blocks) and landed ~30us regardless of internals -> TLP-starved; the
// only lever that ever moved k_s was resident waves (r1->r2).
__global__ __launch_bounds__(256, 6) void k_s(
    const float* __restrict__ u,      // [B][R][8]
    const float* __restrict__ W,      // [R][10][16][8]
    const float* __restrict__ ab,     // [nbuf][YBLK][R][10] agreement partials
    float* __restrict__ part,         // [NSPLIT][B][160]
    float* __restrict__ sq,
    int nbuf)
{
    __shared__ float ut[32 * UPAD];     // 6,528 B
    __shared__ float cs[RPS * DIGITS];  // c for this block's 6 rows

    const int split = blockIdx.x;
    const int b0 = blockIdx.y * 32;
    const int t = threadIdx.x;
    const int o = t & 15;
    const int bs = t >> 4;
    const int r0 = split * RPS;

    if (split == 0 && blockIdx.y == 0 && t == 0) *sq = 0.f;

    // ---- 1. stage u-tile (32 b x 12 f4 = 384 f4, coalesced 192B runs)
#pragma unroll
    for (int p = 0; p < 2; ++p) {
        int idx = t + p * 256;            // 0..511
        if (idx < 32 * 12) {
            int b = idx / 12, q = idx - b * 12;
            float4 v = ((const float4*)(u + (size_t)(b0 + b) * (R_NODES * IN_CH)
                                          + (size_t)r0 * IN_CH))[q];
            *(float4*)&ut[b * UPAD + q * 4] = v;
        }
    }

    // ---- 2. c logits for rows r0..r0+5 (0 if nbuf==0 -> softmax = 0.1)
    if (t < RPS * DIGITS) {
        float a = 0.f;
        int r_l = t / 10, d = t - r_l * 10;
        const float* p0 = ab + (size_t)(r0 + r_l) * DIGITS + d;
        for (int bu = 0; bu < nbuf; ++bu)
#pragma unroll
            for (int yy = 0; yy < YBLK; ++yy)
                a += p0[(size_t)bu * AB_STRIDE + (size_t)yy * (R_NODES * DIGITS)];
        cs[t] = a;
    }
    __syncthreads();
    if (t < RPS) {
        float e[DIGITS];
        float m = -1e30f;
#pragma unroll
        for (int d = 0; d < DIGITS; ++d) m = fmaxf(m, cs[t*10 + d]);
        float ssum = 0.f;
#pragma unroll
        for (int d = 0; d < DIGITS; ++d) { e[d] = expf(cs[t*10 + d] - m); ssum += e[d]; }
        float inv = 1.f / ssum;
#pragma unroll
        for (int d = 0; d < DIGITS; ++d) cs[t*10 + d] = e[d] * inv;
    }
    __syncthreads();

    // ---- 3. main loop: u broadcast from LDS, W streamed global->regs (L1/L2)
    float acc[2][10];
#pragma unroll
    for (int jj = 0; jj < 2; ++jj)
#pragma unroll
        for (int j = 0; j < 10; ++j) acc[jj][j] = 0.f;

    const float* Wb = W + (size_t)r0 * W_PER_R + (size_t)o * IN_CH;

    for (int r_l = 0; r_l < RPS; ++r_l) {
        float4 ua[2], ub2[2];
#pragma unroll
        for (int jj = 0; jj < 2; ++jj) {
            const float* up = &ut[(bs * 2 + jj) * UPAD + r_l * 8];
            ua[jj]  = *(const float4*)up;
            ub2[jj] = *(const float4*)(up + 4);
        }
        const float* Wr = Wb + (size_t)r_l * W_PER_R;
#pragma unroll
        for (int d = 0; d < 10; ++d) {
            const float4* wp = (const float4*)(Wr + d * 128);
            float4 w0 = wp[0], w1 = wp[1];
            float cv = cs[r_l * 10 + d];
#pragma unroll
            for (int jj = 0; jj < 2; ++jj) {
                float uh;
                uh = w0.x * ua[jj].x;
                uh = fmaf(w0.y, ua[jj].y, uh);
                uh = fmaf(w0.z, ua[jj].z, uh);
                uh = fmaf(w0.w, ua[jj].w, uh);
                uh = fmaf(w1.x, ub2[jj].x, uh);
                uh = fmaf(w1.y, ub2[jj].y, uh);
                uh = fmaf(w1.z, ub2[jj].z, uh);
                uh = fmaf(w1.w, ub2[jj].w, uh);
                acc[jj][d] = fmaf(uh, cv, acc[jj][d]);
            }
        }
    }

    // ---- 4. store: part[split][b0+bs*2+jj][d*16+o]
    float* pp = part + (size_t)split * (BATCH * COLS) + (size_t)b0 * COLS;
#pragma unroll
    for (int jj = 0; jj < 2; ++jj) {
        float* row = pp + (size_t)(bs * 2 + jj) * COLS + o;
#pragma unroll
        for (int d = 0; d < 10; ++d) row[d * 16] = acc[jj][d];
    }
}

// ---------- reduce partials -> s ; accumulate global sum of squares ----------
__global__ void k_sq(const float* __restrict__ part,
                     float* __restrict__ s,
                     float* __restrict__ sq)
{
    const int t = threadIdx.x;
    const int e0 = blockIdx.x * 64;
    const int el = t & 63, q = t >> 6;
    float v = 0.f;
    for (int sp = q; sp < NSPLIT; sp += 4)
        v += part[(size_t)sp * (BATCH * COLS) + e0 + el];
    __shared__ float red[256];
    red[t] = v;
    __syncthreads();
    if (t < 64) {
        float vv = red[t] + red[t + 64] + red[t + 128] + red[t + 192];
        s[e0 + t] = vv;
        float x = vv * vv;
#pragma unroll
        for (int off = 32; off > 0; off >>= 1)
            x += __shfl_down(x, off, 64);
        if (t == 0) atomicAdd(sq, x);
    }
}

// ---------- agreement partials: ab[y][r,d] = scale * sum_{b in y,o} u_hat*s ----------
__global__ __launch_bounds__(256) void k_a(
    const float* __restrict__ u,
    const float* __restrict__ W,
    const float* __restrict__ s,
    const float* __restrict__ sq,
    float* __restrict__ ab)
{
    __shared__ float st[32 * COLS];   // 20.5 KB
    __shared__ float ut[32 * 64];     // 8 KB
    const int t = threadIdx.x;
    const int rblk = blockIdx.x;
    const int r = rblk * 8 + (t >> 5);
    const int tt = t & 31;
    const int bstart = blockIdx.y * 32;

    {
        const float4* sp = (const float4*)(s + (size_t)bstart * COLS);
#pragma unroll
        for (int p = 0; p < 5; ++p) ((float4*)st)[t + p * 256] = sp[t + p * 256];
    }
#pragma unroll
    for (int p = 0; p < 2; ++p) {
        int idx = t + p * 256;
        int bb = idx >> 4, qq = idx & 15;
        ((float4*)ut)[idx] =
            ((const float4*)(u + (size_t)(bstart + bb) * (R_NODES*IN_CH) + (size_t)rblk * 64))[qq];
    }

    float wreg[5][8];
#pragma unroll
    for (int k = 0; k < 5; ++k) {
        const float4* wp = (const float4*)(W + (size_t)r * W_PER_R + (size_t)(tt + 32*k) * IN_CH);
        float4 w0 = wp[0], w1 = wp[1];
        wreg[k][0]=w0.x; wreg[k][1]=w0.y; wreg[k][2]=w0.z; wreg[k][3]=w0.w;
        wreg[k][4]=w1.x; wreg[k][5]=w1.y; wreg[k][6]=w1.z; wreg[k][7]=w1.w;
    }
    __syncthreads();

    float acc[5] = {0.f, 0.f, 0.f, 0.f, 0.f};
#pragma unroll 2
    for (int b = 0; b < 32; ++b) {
        const float* ub = &ut[b * 64 + (t >> 5) * 8];
        float4 a0 = *(const float4*)ub;
        float4 a1 = *(const float4*)(ub + 4);
        const float* sb = &st[b * COLS];
#pragma unroll
        for (int k = 0; k < 5; ++k) {
            float vv = sb[tt + 32*k];
            float uh;
            uh = wreg[k][0] * a0.x;
            uh = fmaf(wreg[k][1], a0.y, uh);
            uh = fmaf(wreg[k][2], a0.z, uh);
            uh = fmaf(wreg[k][3], a0.w, uh);
            uh = fmaf(wreg[k][4], a1.x, uh);
            uh = fmaf(wreg[k][5], a1.y, uh);
            uh = fmaf(wreg[k][6], a1.z, uh);
            uh = fmaf(wreg[k][7], a1.w, uh);
            acc[k] = fmaf(uh, vv, acc[k]);
        }
    }
    float q = *sq;
    float scale = sqrtf(q) / (1.f + q);
    float* abp = ab + (size_t)blockIdx.y * (R_NODES * DIGITS) + r * DIGITS;
#pragma unroll
    for (int k = 0; k < 5; ++k) {
        float x = acc[k] * scale;
        x += __shfl_xor(x, 1, 64);
        x += __shfl_xor(x, 2, 64);
        x += __shfl_xor(x, 4, 64);
        x += __shfl_xor(x, 8, 64);
        if ((tt & 15) == 0) {
            int d = (tt >> 4) + 2*k;
            abp[d] = x;
        }
    }
}

// ---------- final output: v = s * sqrt(sq)/(1+sq) ----------
__global__ void k_scale(const float* __restrict__ s,
                        const float* __restrict__ sq,
                        float* __restrict__ out)
{
    int e = blockIdx.x * 256 + threadIdx.x;
    float q = *sq;
    float scale = sqrtf(q) / (1.f + q);
    out[e] = s[e] * scale;
}

extern "C" void kernel_launch(void* const* d_in, const int* in_sizes, int n_in,
                              void* d_out, int out_size, void* d_ws, size_t ws_size,
                              hipStream_t stream)
{
    const float* u = (const float*)d_in[0];   // (256, 1152, 8)
    const float* W = (const float*)d_in[1];   // (1, 1152, 10, 16, 8)
    float* out = (float*)d_out;               // (256, 10, 16)
    float* ws = (float*)d_ws;

    float* s    = ws;                          // 40960 floats
    float* sq   = ws + 40960;                  // 1 (padded to 64)
    float* ab   = ws + 41024;                  // 2 * 92160
    float* part = ws + 41024 + 2 * AB_STRIDE;  // 192 * 40960 (~31.5 MB)

    for (int it = 0; it < 3; ++it) {
        k_s<<<dim3(NSPLIT, YB_S), dim3(256), 0, stream>>>(u, W, ab, part, sq, it);
        k_sq<<<dim3(BATCH * COLS / 64), dim3(256), 0, stream>>>(part, s, sq);
        if (it < 2)
            k_a<<<dim3(R_NODES / 8, YBLK), dim3(256), 0, stream>>>(u, W, s, sq,
                                                                   ab + (size_t)it * AB_STRIDE);
        else
            k_scale<<<dim3(BATCH * COLS / 256), dim3(256), 0, stream>>>(s, sq, out);
    }
}

// Round 15
// 161.699 us; speedup vs baseline: 1.2477x; 1.2477x over previous
//
#include <hip/hip_runtime.h>
#include <math.h>

#define R_NODES 1152
#define DIGITS 10
#define OUT_CH 16
#define IN_CH 8
#define BATCH 256
#define COLS 160            // DIGITS*OUT_CH
#define W_PER_R 1280        // DIGITS*OUT_CH*IN_CH
#define NSPLIT 192          // K-split: 6 r-rows per block
#define RPS 6               // rows per split
#define YBLK 8              // k_a batch blocks (32 b each)
#define UPAD 52             // u-LDS batch stride (48 data + 4 pad): 2-way alias = free
#define AB_STRIDE (YBLK * R_NODES * DIGITS)   // 92160 floats per ab iteration-buffer

// ---------- s partials: o-lane layout, W global->regs (L1), u via LDS ----------
// grid (192, 4) — exact r12 geometry (best: 161.9us).
// r14 post-mortem: the caught k_s dispatch showed VGPR=40, VALU 6%, HBM 18%,
// Occ 13% — the register cap serialized the d-loop into load-pair -> waitcnt
// -> 16 FMA, exposing L2/L3 latency 60x per thread. Fix: hoist W loads in
// groups of 5 d's (10 dwordx4 in flight, ONE waitcnt per group) and relax to
// launch_bounds(256,3) (VGPR cap ~170; grid gives 3 blocks/CU regardless).
__global__ __launch_bounds__(256, 3) void k_s(
    const float* __restrict__ u,      // [B][R][8]
    const float* __restrict__ W,      // [R][10][16][8]
    const float* __restrict__ ab,     // [nbuf][YBLK][R][10] agreement partials
    float* __restrict__ part,         // [NSPLIT][B][160]
    float* __restrict__ sq,
    int nbuf)
{
    __shared__ float ut[64 * UPAD];     // 13,312 B
    __shared__ float cs[RPS * DIGITS];  // c for this block's 6 rows

    const int split = blockIdx.x;
    const int b0 = blockIdx.y * 64;
    const int t = threadIdx.x;
    const int o = t & 15;
    const int bs = t >> 4;
    const int r0 = split * RPS;

    if (split == 0 && blockIdx.y == 0 && t == 0) *sq = 0.f;

    // ---- 1. stage u-tile (3 float4/thread, coalesced 192B runs per batch)
    float4 ur[3]; int ub_[3], uq_[3];
#pragma unroll
    for (int p = 0; p < 3; ++p) {
        int idx = t + p * 256;            // 0..767
        int b = idx / 12, q = idx - b * 12;   // batch 0..63, float4 0..11
        ub_[p] = b; uq_[p] = q;
        ur[p] = ((const float4*)(u + (size_t)(b0 + b) * (R_NODES * IN_CH)
                                   + (size_t)r0 * IN_CH))[q];
    }
#pragma unroll
    for (int p = 0; p < 3; ++p)
        *(float4*)&ut[ub_[p] * UPAD + uq_[p] * 4] = ur[p];

    // ---- 2. c logits for rows r0..r0+5 (0 if nbuf==0 -> softmax = 0.1)
    if (t < RPS * DIGITS) {
        float a = 0.f;
        int r_l = t / 10, d = t - r_l * 10;
        const float* p0 = ab + (size_t)(r0 + r_l) * DIGITS + d;
        for (int bu = 0; bu < nbuf; ++bu)
#pragma unroll
            for (int yy = 0; yy < YBLK; ++yy)
                a += p0[(size_t)bu * AB_STRIDE + (size_t)yy * (R_NODES * DIGITS)];
        cs[t] = a;
    }
    __syncthreads();
    if (t < RPS) {
        float e[DIGITS];
        float m = -1e30f;
#pragma unroll
        for (int d = 0; d < DIGITS; ++d) m = fmaxf(m, cs[t*10 + d]);
        float ssum = 0.f;
#pragma unroll
        for (int d = 0; d < DIGITS; ++d) { e[d] = expf(cs[t*10 + d] - m); ssum += e[d]; }
        float inv = 1.f / ssum;
#pragma unroll
        for (int d = 0; d < DIGITS; ++d) cs[t*10 + d] = e[d] * inv;
    }
    __syncthreads();

    // ---- 3. main loop: u broadcast from LDS; W streamed with 10-deep ILP
    float acc[4][10];
#pragma unroll
    for (int jj = 0; jj < 4; ++jj)
#pragma unroll
        for (int j = 0; j < 10; ++j) acc[jj][j] = 0.f;

    const float* Wb = W + (size_t)r0 * W_PER_R + (size_t)o * IN_CH;

    for (int r_l = 0; r_l < RPS; ++r_l) {
        float4 ua[4], ub2[4];
#pragma unroll
        for (int jj = 0; jj < 4; ++jj) {
            const float* up = &ut[(bs + jj * 16) * UPAD + r_l * 8];
            ua[jj]  = *(const float4*)up;
            ub2[jj] = *(const float4*)(up + 4);
        }
        const float* Wr = Wb + (size_t)r_l * W_PER_R;
#pragma unroll
        for (int dh = 0; dh < 2; ++dh) {
            // hoist 5 d's worth of W (10 dwordx4 issued back-to-back)
            float4 w[10];
#pragma unroll
            for (int dd = 0; dd < 5; ++dd) {
                const float4* wp = (const float4*)(Wr + (dh * 5 + dd) * 128);
                w[2*dd]     = wp[0];
                w[2*dd + 1] = wp[1];
            }
#pragma unroll
            for (int dd = 0; dd < 5; ++dd) {
                const int d = dh * 5 + dd;
                float4 w0 = w[2*dd], w1 = w[2*dd + 1];
                float cv = cs[r_l * 10 + d];
#pragma unroll
                for (int jj = 0; jj < 4; ++jj) {
                    float uh;
                    uh = w0.x * ua[jj].x;
                    uh = fmaf(w0.y, ua[jj].y, uh);
                    uh = fmaf(w0.z, ua[jj].z, uh);
                    uh = fmaf(w0.w, ua[jj].w, uh);
                    uh = fmaf(w1.x, ub2[jj].x, uh);
                    uh = fmaf(w1.y, ub2[jj].y, uh);
                    uh = fmaf(w1.z, ub2[jj].z, uh);
                    uh = fmaf(w1.w, ub2[jj].w, uh);
                    acc[jj][d] = fmaf(uh, cv, acc[jj][d]);
                }
            }
        }
    }

    // ---- 4. store: part[split][b0+bs+16jj][d*16+o]
    float* pp = part + (size_t)split * (BATCH * COLS) + (size_t)b0 * COLS;
#pragma unroll
    for (int jj = 0; jj < 4; ++jj) {
        float* row = pp + (size_t)(bs + jj * 16) * COLS + o;
#pragma unroll
        for (int d = 0; d < 10; ++d) row[d * 16] = acc[jj][d];
    }
}

// ---------- reduce partials -> s ; accumulate global sum of squares ----------
__global__ void k_sq(const float* __restrict__ part,
                     float* __restrict__ s,
                     float* __restrict__ sq)
{
    const int t = threadIdx.x;
    const int e0 = blockIdx.x * 64;
    const int el = t & 63, q = t >> 6;
    float v = 0.f;
    for (int sp = q; sp < NSPLIT; sp += 4)
        v += part[(size_t)sp * (BATCH * COLS) + e0 + el];
    __shared__ float red[256];
    red[t] = v;
    __syncthreads();
    if (t < 64) {
        float vv = red[t] + red[t + 64] + red[t + 128] + red[t + 192];
        s[e0 + t] = vv;
        float x = vv * vv;
#pragma unroll
        for (int off = 32; off > 0; off >>= 1)
            x += __shfl_down(x, off, 64);
        if (t == 0) atomicAdd(sq, x);
    }
}

// ---------- agreement partials: ab[y][r,d] = scale * sum_{b in y,o} u_hat*s ----------
__global__ __launch_bounds__(256) void k_a(
    const float* __restrict__ u,
    const float* __restrict__ W,
    const float* __restrict__ s,
    const float* __restrict__ sq,
    float* __restrict__ ab)
{
    __shared__ float st[32 * COLS];   // 20.5 KB
    __shared__ float ut[32 * 64];     // 8 KB
    const int t = threadIdx.x;
    const int rblk = blockIdx.x;
    const int r = rblk * 8 + (t >> 5);
    const int tt = t & 31;
    const int bstart = blockIdx.y * 32;

    {
        const float4* sp = (const float4*)(s + (size_t)bstart * COLS);
#pragma unroll
        for (int p = 0; p < 5; ++p) ((float4*)st)[t + p * 256] = sp[t + p * 256];
    }
#pragma unroll
    for (int p = 0; p < 2; ++p) {
        int idx = t + p * 256;
        int bb = idx >> 4, qq = idx & 15;
        ((float4*)ut)[idx] =
            ((const float4*)(u + (size_t)(bstart + bb) * (R_NODES*IN_CH) + (size_t)rblk * 64))[qq];
    }

    float wreg[5][8];
#pragma unroll
    for (int k = 0; k < 5; ++k) {
        const float4* wp = (const float4*)(W + (size_t)r * W_PER_R + (size_t)(tt + 32*k) * IN_CH);
        float4 w0 = wp[0], w1 = wp[1];
        wreg[k][0]=w0.x; wreg[k][1]=w0.y; wreg[k][2]=w0.z; wreg[k][3]=w0.w;
        wreg[k][4]=w1.x; wreg[k][5]=w1.y; wreg[k][6]=w1.z; wreg[k][7]=w1.w;
    }
    __syncthreads();

    float acc[5] = {0.f, 0.f, 0.f, 0.f, 0.f};
#pragma unroll 2
    for (int b = 0; b < 32; ++b) {
        const float* ub = &ut[b * 64 + (t >> 5) * 8];
        float4 a0 = *(const float4*)ub;
        float4 a1 = *(const float4*)(ub + 4);
        const float* sb = &st[b * COLS];
#pragma unroll
        for (int k = 0; k < 5; ++k) {
            float vv = sb[tt + 32*k];
            float uh;
            uh = wreg[k][0] * a0.x;
            uh = fmaf(wreg[k][1], a0.y, uh);
            uh = fmaf(wreg[k][2], a0.z, uh);
            uh = fmaf(wreg[k][3], a0.w, uh);
            uh = fmaf(wreg[k][4], a1.x, uh);
            uh = fmaf(wreg[k][5], a1.y, uh);
            uh = fmaf(wreg[k][6], a1.z, uh);
            uh = fmaf(wreg[k][7], a1.w, uh);
            acc[k] = fmaf(uh, vv, acc[k]);
        }
    }
    float q = *sq;
    float scale = sqrtf(q) / (1.f + q);
    float* abp = ab + (size_t)blockIdx.y * (R_NODES * DIGITS) + r * DIGITS;
#pragma unroll
    for (int k = 0; k < 5; ++k) {
        float x = acc[k] * scale;
        x += __shfl_xor(x, 1, 64);
        x += __shfl_xor(x, 2, 64);
        x += __shfl_xor(x, 4, 64);
        x += __shfl_xor(x, 8, 64);
        if ((tt & 15) == 0) {
            int d = (tt >> 4) + 2*k;
            abp[d] = x;
        }
    }
}

// ---------- final output: v = s * sqrt(sq)/(1+sq) ----------
__global__ void k_scale(const float* __restrict__ s,
                        const float* __restrict__ sq,
                        float* __restrict__ out)
{
    int e = blockIdx.x * 256 + threadIdx.x;
    float q = *sq;
    float scale = sqrtf(q) / (1.f + q);
    out[e] = s[e] * scale;
}

extern "C" void kernel_launch(void* const* d_in, const int* in_sizes, int n_in,
                              void* d_out, int out_size, void* d_ws, size_t ws_size,
                              hipStream_t stream)
{
    const float* u = (const float*)d_in[0];   // (256, 1152, 8)
    const float* W = (const float*)d_in[1];   // (1, 1152, 10, 16, 8)
    float* out = (float*)d_out;               // (256, 10, 16)
    float* ws = (float*)d_ws;

    float* s    = ws;                          // 40960 floats
    float* sq   = ws + 40960;                  // 1 (padded to 64)
    float* ab   = ws + 41024;                  // 2 * 92160
    float* part = ws + 41024 + 2 * AB_STRIDE;  // 192 * 40960 (~31.5 MB)

    for (int it = 0; it < 3; ++it) {
        k_s<<<dim3(NSPLIT, 4), dim3(256), 0, stream>>>(u, W, ab, part, sq, it);
        k_sq<<<dim3(BATCH * COLS / 64), dim3(256), 0, stream>>>(part, s, sq);
        if (it < 2)
            k_a<<<dim3(R_NODES / 8, YBLK), dim3(256), 0, stream>>>(u, W, s, sq,
                                                                   ab + (size_t)it * AB_STRIDE);
        else
            k_scale<<<dim3(BATCH * COLS / 256), dim3(256), 0, stream>>>(s, sq, out);
    }
}

// Round 16
// 124.326 us; speedup vs baseline: 1.6228x; 1.3006x over previous
//
#include <hip/hip_runtime.h>
#include <math.h>

#define R_NODES 1152
#define DIGITS 10
#define OUT_CH 16
#define IN_CH 8
#define BATCH 256
#define COLS 160            // DIGITS*OUT_CH
#define W_PER_R 1280        // DIGITS*OUT_CH*IN_CH
#define NSPLIT 144          // K-split: 8 r-rows (K=64) per block
#define RPS 8               // rows per split
#define YBLK 8              // k_a batch blocks (32 b each)
#define UP 88               // bf16 LDS row stride: 176B = 16B-aligned, bank-stride 12 -> 2-way (free)
#define AB_STRIDE (YBLK * R_NODES * DIGITS)   // 92160 floats per ab iteration-buffer

typedef __attribute__((ext_vector_type(8))) short short8v;
typedef __attribute__((ext_vector_type(4))) float floatx4;

__device__ inline unsigned short f2bf(float x) {
    union { float f; unsigned int i; } v; v.f = x;
    unsigned int r = v.i + 0x7FFFu + ((v.i >> 16) & 1u);   // round-nearest-even
    return (unsigned short)(r >> 16);
}

// ---------- s partials via MFMA: s[b,col] = sum_K u_bf16[b,K] * Wc_bf16[K,col] ----------
// grid (144, 4): blockIdx.x = K-chunk (8 r-rows = K 64), blockIdx.y = 64-batch block.
// r15 post-mortem: 6 consecutive k_s-internal experiments were nulls (+-3%);
// switch engines entirely. bf16 MFMA is in-budget: threshold 4.785e-4 is
// bf16-level, error est |dv| ~ 3e-5. Per block: stage u (64x64) and c-folded
// W (64x160) as bf16 LDS (stride 88: 16B-aligned b128 frag reads, 2-way alias
// = free), then 4 waves x 10 tiles x 2 mfma_f32_16x16x32_bf16.
// Frag maps: A/B lane%16 = non-K idx, k = (lane/16)*8+j; D col=lane&15,
// row=(lane>>4)*4+reg [m89-verified].
__global__ __launch_bounds__(256, 3) void k_s(
    const float* __restrict__ u,      // [B][R][8]
    const float* __restrict__ W,      // [R][10][16][8]
    const float* __restrict__ ab,     // [nbuf][YBLK][R][10] agreement partials
    float* __restrict__ part,         // [NSPLIT][B][160]
    float* __restrict__ sq,
    int nbuf)
{
    __shared__ unsigned short ulds[64 * UP];    // 11.3 KB  [batch][K]
    __shared__ unsigned short wlds[COLS * UP];  // 28.2 KB  [col][K]
    __shared__ float cs[RPS * DIGITS];          // 80 logits -> c

    const int split = blockIdx.x;
    const int b0 = blockIdx.y * 64;
    const int t = threadIdx.x;
    const int r0 = split * RPS;

    if (split == 0 && blockIdx.y == 0 && t == 0) *sq = 0.f;

    // ---- 1. stage u: 64 b x 64 K fp32 -> bf16 (coalesced 256B runs per batch)
#pragma unroll
    for (int p = 0; p < 4; ++p) {
        int idx = t + p * 256;            // 0..1023 f4
        int b = idx >> 4, q = idx & 15;   // batch, f4-within-64-floats
        float4 v = *(const float4*)(u + (size_t)(b0 + b) * (R_NODES * IN_CH)
                                      + (size_t)r0 * IN_CH + q * 4);
        *(short4*)&ulds[b * UP + q * 4] =
            make_short4((short)f2bf(v.x), (short)f2bf(v.y),
                        (short)f2bf(v.z), (short)f2bf(v.w));
    }

    // ---- 2. issue W loads (10 f4/thread, held in regs across softmax)
    float4 wr[10];
    {
        const float4* Wg = (const float4*)(W + (size_t)r0 * W_PER_R);
#pragma unroll
        for (int p = 0; p < 10; ++p) wr[p] = Wg[t + p * 256];
    }

    // ---- 3. c logits for rows r0..r0+7 (0 if nbuf==0 -> softmax = 0.1)
    if (t < RPS * DIGITS) {
        float a = 0.f;
        int r_l = t / 10, d = t - r_l * 10;
        const float* p0 = ab + (size_t)(r0 + r_l) * DIGITS + d;
        for (int bu = 0; bu < nbuf; ++bu)
#pragma unroll
            for (int yy = 0; yy < YBLK; ++yy)
                a += p0[(size_t)bu * AB_STRIDE + (size_t)yy * (R_NODES * DIGITS)];
        cs[t] = a;
    }
    __syncthreads();
    if (t < RPS) {
        float e[DIGITS];
        float m = -1e30f;
#pragma unroll
        for (int d = 0; d < DIGITS; ++d) m = fmaxf(m, cs[t*10 + d]);
        float ssum = 0.f;
#pragma unroll
        for (int d = 0; d < DIGITS; ++d) { e[d] = expf(cs[t*10 + d] - m); ssum += e[d]; }
        float inv = 1.f / ssum;
#pragma unroll
        for (int d = 0; d < DIGITS; ++d) cs[t*10 + d] = e[d] * inv;
    }
    __syncthreads();

    // ---- 4. fold c, cvt bf16, write wlds[col][K] (B^T layout for frag reads)
#pragma unroll
    for (int p = 0; p < 10; ++p) {
        int e4 = t + p * 256;             // f4 idx 0..2559 over 8 rows
        int e  = e4 * 4;
        int r_l = e4 / 320;               // 320 f4 per W row
        int rem = e - r_l * W_PER_R;
        int col = rem >> 3;               // d*16+o
        int i0  = e & 7;                  // 0 or 4
        float cv = cs[r_l * 10 + (rem >> 7)];
        float4 w4 = wr[p];
        *(short4*)&wlds[col * UP + r_l * 8 + i0] =
            make_short4((short)f2bf(w4.x * cv), (short)f2bf(w4.y * cv),
                        (short)f2bf(w4.z * cv), (short)f2bf(w4.w * cv));
    }
    __syncthreads();

    // ---- 5. MFMA: wave w owns batch rows w*16..+15 x all 160 cols (10 tiles)
    const int w = t >> 6, l = t & 63;
    const int koff = (l >> 4) * 8;
    const int arow = (w * 16 + (l & 15)) * UP;
    short8v a0 = *(const short8v*)&ulds[arow + koff];
    short8v a1 = *(const short8v*)&ulds[arow + 32 + koff];

    float* pp = part + (size_t)split * (BATCH * COLS);
    const int gb = b0 + w * 16 + (l >> 4) * 4;
#pragma unroll
    for (int j = 0; j < 10; ++j) {
        const int bcol = (j * 16 + (l & 15)) * UP;
        short8v bb0 = *(const short8v*)&wlds[bcol + koff];
        short8v bb1 = *(const short8v*)&wlds[bcol + 32 + koff];
        floatx4 c = {0.f, 0.f, 0.f, 0.f};
        c = __builtin_amdgcn_mfma_f32_16x16x32_bf16(a0, bb0, c, 0, 0, 0);
        c = __builtin_amdgcn_mfma_f32_16x16x32_bf16(a1, bb1, c, 0, 0, 0);
        const int gc = j * 16 + (l & 15);
#pragma unroll
        for (int reg = 0; reg < 4; ++reg)
            pp[(size_t)(gb + reg) * COLS + gc] = c[reg];
    }
}

// ---------- reduce partials -> s ; accumulate global sum of squares ----------
__global__ void k_sq(const float* __restrict__ part,
                     float* __restrict__ s,
                     float* __restrict__ sq)
{
    const int t = threadIdx.x;
    const int e0 = blockIdx.x * 64;
    const int el = t & 63, q = t >> 6;
    float v = 0.f;
    for (int sp = q; sp < NSPLIT; sp += 4)
        v += part[(size_t)sp * (BATCH * COLS) + e0 + el];
    __shared__ float red[256];
    red[t] = v;
    __syncthreads();
    if (t < 64) {
        float vv = red[t] + red[t + 64] + red[t + 128] + red[t + 192];
        s[e0 + t] = vv;
        float x = vv * vv;
#pragma unroll
        for (int off = 32; off > 0; off >>= 1)
            x += __shfl_down(x, off, 64);
        if (t == 0) atomicAdd(sq, x);
    }
}

// ---------- agreement partials: ab[y][r,d] = scale * sum_{b in y,o} u_hat*s ----------
__global__ __launch_bounds__(256) void k_a(
    const float* __restrict__ u,
    const float* __restrict__ W,
    const float* __restrict__ s,
    const float* __restrict__ sq,
    float* __restrict__ ab)
{
    __shared__ float st[32 * COLS];   // 20.5 KB
    __shared__ float ut[32 * 64];     // 8 KB
    const int t = threadIdx.x;
    const int rblk = blockIdx.x;
    const int r = rblk * 8 + (t >> 5);
    const int tt = t & 31;
    const int bstart = blockIdx.y * 32;

    {
        const float4* sp = (const float4*)(s + (size_t)bstart * COLS);
#pragma unroll
        for (int p = 0; p < 5; ++p) ((float4*)st)[t + p * 256] = sp[t + p * 256];
    }
#pragma unroll
    for (int p = 0; p < 2; ++p) {
        int idx = t + p * 256;
        int bb = idx >> 4, qq = idx & 15;
        ((float4*)ut)[idx] =
            ((const float4*)(u + (size_t)(bstart + bb) * (R_NODES*IN_CH) + (size_t)rblk * 64))[qq];
    }

    float wreg[5][8];
#pragma unroll
    for (int k = 0; k < 5; ++k) {
        const float4* wp = (const float4*)(W + (size_t)r * W_PER_R + (size_t)(tt + 32*k) * IN_CH);
        float4 w0 = wp[0], w1 = wp[1];
        wreg[k][0]=w0.x; wreg[k][1]=w0.y; wreg[k][2]=w0.z; wreg[k][3]=w0.w;
        wreg[k][4]=w1.x; wreg[k][5]=w1.y; wreg[k][6]=w1.z; wreg[k][7]=w1.w;
    }
    __syncthreads();

    float acc[5] = {0.f, 0.f, 0.f, 0.f, 0.f};
#pragma unroll 2
    for (int b = 0; b < 32; ++b) {
        const float* ub = &ut[b * 64 + (t >> 5) * 8];
        float4 a0 = *(const float4*)ub;
        float4 a1 = *(const float4*)(ub + 4);
        const float* sb = &st[b * COLS];
#pragma unroll
        for (int k = 0; k < 5; ++k) {
            float vv = sb[tt + 32*k];
            float uh;
            uh = wreg[k][0] * a0.x;
            uh = fmaf(wreg[k][1], a0.y, uh);
            uh = fmaf(wreg[k][2], a0.z, uh);
            uh = fmaf(wreg[k][3], a0.w, uh);
            uh = fmaf(wreg[k][4], a1.x, uh);
            uh = fmaf(wreg[k][5], a1.y, uh);
            uh = fmaf(wreg[k][6], a1.z, uh);
            uh = fmaf(wreg[k][7], a1.w, uh);
            acc[k] = fmaf(uh, vv, acc[k]);
        }
    }
    float q = *sq;
    float scale = sqrtf(q) / (1.f + q);
    float* abp = ab + (size_t)blockIdx.y * (R_NODES * DIGITS) + r * DIGITS;
#pragma unroll
    for (int k = 0; k < 5; ++k) {
        float x = acc[k] * scale;
        x += __shfl_xor(x, 1, 64);
        x += __shfl_xor(x, 2, 64);
        x += __shfl_xor(x, 4, 64);
        x += __shfl_xor(x, 8, 64);
        if ((tt & 15) == 0) {
            int d = (tt >> 4) + 2*k;
            abp[d] = x;
        }
    }
}

// ---------- final output: v = s * sqrt(sq)/(1+sq) ----------
__global__ void k_scale(const float* __restrict__ s,
                        const float* __restrict__ sq,
                        float* __restrict__ out)
{
    int e = blockIdx.x * 256 + threadIdx.x;
    float q = *sq;
    float scale = sqrtf(q) / (1.f + q);
    out[e] = s[e] * scale;
}

extern "C" void kernel_launch(void* const* d_in, const int* in_sizes, int n_in,
                              void* d_out, int out_size, void* d_ws, size_t ws_size,
                              hipStream_t stream)
{
    const float* u = (const float*)d_in[0];   // (256, 1152, 8)
    const float* W = (const float*)d_in[1];   // (1, 1152, 10, 16, 8)
    float* out = (float*)d_out;               // (256, 10, 16)
    float* ws = (float*)d_ws;

    float* s    = ws;                          // 40960 floats
    float* sq   = ws + 40960;                  // 1 (padded to 64)
    float* ab   = ws + 41024;                  // 2 * 92160
    float* part = ws + 41024 + 2 * AB_STRIDE;  // 144 * 40960 (~23.6 MB)

    for (int it = 0; it < 3; ++it) {
        k_s<<<dim3(NSPLIT, 4), dim3(256), 0, stream>>>(u, W, ab, part, sq, it);
        k_sq<<<dim3(BATCH * COLS / 64), dim3(256), 0, stream>>>(part, s, sq);
        if (it < 2)
            k_a<<<dim3(R_NODES / 8, YBLK), dim3(256), 0, stream>>>(u, W, s, sq,
                                                                   ab + (size_t)it * AB_STRIDE);
        else
            k_scale<<<dim3(BATCH * COLS / 256), dim3(256), 0, stream>>>(s, sq, out);
    }
}

// Round 17
// 102.500 us; speedup vs baseline: 1.9684x; 1.2129x over previous
//
#include <hip/hip_runtime.h>
#include <math.h>

#define R_NODES 1152
#define DIGITS 10
#define OUT_CH 16
#define IN_CH 8
#define BATCH 256
#define COLS 160            // DIGITS*OUT_CH
#define W_PER_R 1280        // DIGITS*OUT_CH*IN_CH
#define NSPLIT 72           // K-split: 16 r-rows (K=128, 2 chunks) per block
#define RPS 16              // rows per split
#define YB_S 8              // k_s batch blocks (32 b each)
#define YBLK 8              // k_a batch blocks (32 b each)
#define UP 88               // bf16 LDS row stride (holds 64 K): 176B, 2-way alias = free
#define AB_STRIDE (YBLK * R_NODES * DIGITS)   // 92160 floats per ab iteration-buffer

typedef __attribute__((ext_vector_type(8))) short short8v;
typedef __attribute__((ext_vector_type(4))) float floatx4;

__device__ inline unsigned short f2bf(float x) {
    union { float f; unsigned int i; } v; v.f = x;
    unsigned int r = v.i + 0x7FFFu + ((v.i >> 16) & 1u);   // round-nearest-even
    return (unsigned short)(r >> 16);
}
__device__ inline float bf2f(unsigned short x) {
    union { unsigned int i; float f; } v; v.i = ((unsigned int)x) << 16;
    return v.f;
}

// ---------- s partials via MFMA, 2-chunk K-loop, bf16 part ----------
// grid (72, 8): blockIdx.x = K-chunk-pair (16 r-rows = K 128), blockIdx.y = 32-batch.
// r16 analysis: k_s became staging/traffic-bound — part (23.6MB) written +
// read back per iteration dominated. This round: K=128/block (2 chunks of 64
// accumulated in MFMA acc regs, §5 K-loop recipe) halves NSPLIT, and part is
// bf16 (error budget: 0.013/partial * sqrt(72) = 0.11 abs on |s|~9.6 ->
// dv ~ 5.6e-5 << 4.8e-4 threshold). part round-trip: 47 -> 11.8 MB/iter.
// 4 waves: wave w -> M-tile (w&1), N-tiles (w>>1)*5..+5; 10 MFMA/wave/chunk.
__global__ __launch_bounds__(256, 3) void k_s(
    const float* __restrict__ u,      // [B][R][8]
    const float* __restrict__ W,      // [R][10][16][8]
    const float* __restrict__ ab,     // [nbuf][YBLK][R][10] agreement partials
    unsigned short* __restrict__ part, // [NSPLIT][B][160] bf16
    float* __restrict__ sq,
    int nbuf)
{
    __shared__ unsigned short ulds[32 * UP];    // 5.6 KB  [batch][K-chunk]
    __shared__ unsigned short wlds[COLS * UP];  // 28.2 KB [col][K-chunk]
    __shared__ float cs[RPS * DIGITS];          // 160 logits -> c

    const int split = blockIdx.x;
    const int b0 = blockIdx.y * 32;
    const int t = threadIdx.x;
    const int r0 = split * RPS;

    if (split == 0 && blockIdx.y == 0 && t == 0) *sq = 0.f;

    // ---- 1. c logits for rows r0..r0+15 (0 if nbuf==0 -> softmax = 0.1)
    if (t < RPS * DIGITS) {
        float a = 0.f;
        int r_l = t / 10, d = t - r_l * 10;
        const float* p0 = ab + (size_t)(r0 + r_l) * DIGITS + d;
        for (int bu = 0; bu < nbuf; ++bu)
#pragma unroll
            for (int yy = 0; yy < YBLK; ++yy)
                a += p0[(size_t)bu * AB_STRIDE + (size_t)yy * (R_NODES * DIGITS)];
        cs[t] = a;
    }
    __syncthreads();
    if (t < RPS) {
        float e[DIGITS];
        float m = -1e30f;
#pragma unroll
        for (int d = 0; d < DIGITS; ++d) m = fmaxf(m, cs[t*10 + d]);
        float ssum = 0.f;
#pragma unroll
        for (int d = 0; d < DIGITS; ++d) { e[d] = expf(cs[t*10 + d] - m); ssum += e[d]; }
        float inv = 1.f / ssum;
#pragma unroll
        for (int d = 0; d < DIGITS; ++d) cs[t*10 + d] = e[d] * inv;
    }
    __syncthreads();

    // ---- 2. MFMA geometry (constant per thread)
    const int w = t >> 6, l = t & 63;
    const int mtile = w & 1;
    const int ncol0 = (w >> 1) * 5;
    const int koff = (l >> 4) * 8;
    const int arow = (mtile * 16 + (l & 15)) * UP;

    floatx4 acc[5];
#pragma unroll
    for (int j = 0; j < 5; ++j) acc[j] = (floatx4){0.f, 0.f, 0.f, 0.f};

    // ---- 3. K-chunk loop: stage chunk (8 r-rows = K 64) -> MFMA-accumulate
    for (int ch = 0; ch < 2; ++ch) {
        const int rc = r0 + ch * 8;
        // issue u chunk loads (2 f4/thread: 32 b x 16 f4)
        float4 uv[2];
#pragma unroll
        for (int p = 0; p < 2; ++p) {
            int idx = t + p * 256;            // 0..511
            int b = idx >> 4, q = idx & 15;
            uv[p] = *(const float4*)(u + (size_t)(b0 + b) * (R_NODES * IN_CH)
                                       + (size_t)rc * IN_CH + q * 4);
        }
        // issue W chunk loads (10 f4/thread: 8 rows x 320 f4)
        float4 wr[10];
        {
            const float4* Wg = (const float4*)(W + (size_t)rc * W_PER_R);
#pragma unroll
            for (int p = 0; p < 10; ++p) wr[p] = Wg[t + p * 256];
        }
        if (ch) __syncthreads();   // prev chunk's MFMA readers done
        // write u chunk
#pragma unroll
        for (int p = 0; p < 2; ++p) {
            int idx = t + p * 256;
            int b = idx >> 4, q = idx & 15;
            *(short4*)&ulds[b * UP + q * 4] =
                make_short4((short)f2bf(uv[p].x), (short)f2bf(uv[p].y),
                            (short)f2bf(uv[p].z), (short)f2bf(uv[p].w));
        }
        // write W chunk (c-folded, [col][K] B^T layout)
#pragma unroll
        for (int p = 0; p < 10; ++p) {
            int e4 = t + p * 256;             // f4 idx 0..2559 over 8 rows
            int e  = e4 * 4;
            int r_l = e4 / 320;               // 0..7
            int rem = e - r_l * W_PER_R;
            int col = rem >> 3;               // d*16+o
            int i0  = e & 7;
            float cv = cs[(ch * 8 + r_l) * 10 + (rem >> 7)];
            float4 w4 = wr[p];
            *(short4*)&wlds[col * UP + r_l * 8 + i0] =
                make_short4((short)f2bf(w4.x * cv), (short)f2bf(w4.y * cv),
                            (short)f2bf(w4.z * cv), (short)f2bf(w4.w * cv));
        }
        __syncthreads();
        // MFMA accumulate
        short8v a0 = *(const short8v*)&ulds[arow + koff];
        short8v a1 = *(const short8v*)&ulds[arow + 32 + koff];
#pragma unroll
        for (int j = 0; j < 5; ++j) {
            const int bcol = ((ncol0 + j) * 16 + (l & 15)) * UP;
            short8v bb0 = *(const short8v*)&wlds[bcol + koff];
            short8v bb1 = *(const short8v*)&wlds[bcol + 32 + koff];
            acc[j] = __builtin_amdgcn_mfma_f32_16x16x32_bf16(a0, bb0, acc[j], 0, 0, 0);
            acc[j] = __builtin_amdgcn_mfma_f32_16x16x32_bf16(a1, bb1, acc[j], 0, 0, 0);
        }
    }

    // ---- 4. store bf16: part[split][gb+reg][gc]
    unsigned short* pp = part + (size_t)split * (BATCH * COLS);
    const int gb = b0 + mtile * 16 + (l >> 4) * 4;
#pragma unroll
    for (int j = 0; j < 5; ++j) {
        const int gc = (ncol0 + j) * 16 + (l & 15);
#pragma unroll
        for (int reg = 0; reg < 4; ++reg)
            pp[(size_t)(gb + reg) * COLS + gc] = f2bf(acc[j][reg]);
    }
}

// ---------- reduce bf16 partials -> s ; accumulate global sum of squares ----------
__global__ void k_sq(const unsigned short* __restrict__ part,
                     float* __restrict__ s,
                     float* __restrict__ sq)
{
    const int t = threadIdx.x;
    const int e0 = blockIdx.x * 64;
    const int el = t & 63, q = t >> 6;
    float v = 0.f;
    for (int sp = q; sp < NSPLIT; sp += 4)
        v += bf2f(part[(size_t)sp * (BATCH * COLS) + e0 + el]);
    __shared__ float red[256];
    red[t] = v;
    __syncthreads();
    if (t < 64) {
        float vv = red[t] + red[t + 64] + red[t + 128] + red[t + 192];
        s[e0 + t] = vv;
        float x = vv * vv;
#pragma unroll
        for (int off = 32; off > 0; off >>= 1)
            x += __shfl_down(x, off, 64);
        if (t == 0) atomicAdd(sq, x);
    }
}

// ---------- agreement partials: ab[y][r,d] = scale * sum_{b in y,o} u_hat*s ----------
__global__ __launch_bounds__(256) void k_a(
    const float* __restrict__ u,
    const float* __restrict__ W,
    const float* __restrict__ s,
    const float* __restrict__ sq,
    float* __restrict__ ab)
{
    __shared__ float st[32 * COLS];   // 20.5 KB
    __shared__ float ut[32 * 64];     // 8 KB
    const int t = threadIdx.x;
    const int rblk = blockIdx.x;
    const int r = rblk * 8 + (t >> 5);
    const int tt = t & 31;
    const int bstart = blockIdx.y * 32;

    {
        const float4* sp = (const float4*)(s + (size_t)bstart * COLS);
#pragma unroll
        for (int p = 0; p < 5; ++p) ((float4*)st)[t + p * 256] = sp[t + p * 256];
    }
#pragma unroll
    for (int p = 0; p < 2; ++p) {
        int idx = t + p * 256;
        int bb = idx >> 4, qq = idx & 15;
        ((float4*)ut)[idx] =
            ((const float4*)(u + (size_t)(bstart + bb) * (R_NODES*IN_CH) + (size_t)rblk * 64))[qq];
    }

    float wreg[5][8];
#pragma unroll
    for (int k = 0; k < 5; ++k) {
        const float4* wp = (const float4*)(W + (size_t)r * W_PER_R + (size_t)(tt + 32*k) * IN_CH);
        float4 w0 = wp[0], w1 = wp[1];
        wreg[k][0]=w0.x; wreg[k][1]=w0.y; wreg[k][2]=w0.z; wreg[k][3]=w0.w;
        wreg[k][4]=w1.x; wreg[k][5]=w1.y; wreg[k][6]=w1.z; wreg[k][7]=w1.w;
    }
    __syncthreads();

    float acc[5] = {0.f, 0.f, 0.f, 0.f, 0.f};
#pragma unroll 2
    for (int b = 0; b < 32; ++b) {
        const float* ub = &ut[b * 64 + (t >> 5) * 8];
        float4 a0 = *(const float4*)ub;
        float4 a1 = *(const float4*)(ub + 4);
        const float* sb = &st[b * COLS];
#pragma unroll
        for (int k = 0; k < 5; ++k) {
            float vv = sb[tt + 32*k];
            float uh;
            uh = wreg[k][0] * a0.x;
            uh = fmaf(wreg[k][1], a0.y, uh);
            uh = fmaf(wreg[k][2], a0.z, uh);
            uh = fmaf(wreg[k][3], a0.w, uh);
            uh = fmaf(wreg[k][4], a1.x, uh);
            uh = fmaf(wreg[k][5], a1.y, uh);
            uh = fmaf(wreg[k][6], a1.z, uh);
            uh = fmaf(wreg[k][7], a1.w, uh);
            acc[k] = fmaf(uh, vv, acc[k]);
        }
    }
    float q = *sq;
    float scale = sqrtf(q) / (1.f + q);
    float* abp = ab + (size_t)blockIdx.y * (R_NODES * DIGITS) + r * DIGITS;
#pragma unroll
    for (int k = 0; k < 5; ++k) {
        float x = acc[k] * scale;
        x += __shfl_xor(x, 1, 64);
        x += __shfl_xor(x, 2, 64);
        x += __shfl_xor(x, 4, 64);
        x += __shfl_xor(x, 8, 64);
        if ((tt & 15) == 0) {
            int d = (tt >> 4) + 2*k;
            abp[d] = x;
        }
    }
}

// ---------- final output: v = s * sqrt(sq)/(1+sq) ----------
__global__ void k_scale(const float* __restrict__ s,
                        const float* __restrict__ sq,
                        float* __restrict__ out)
{
    int e = blockIdx.x * 256 + threadIdx.x;
    float q = *sq;
    float scale = sqrtf(q) / (1.f + q);
    out[e] = s[e] * scale;
}

extern "C" void kernel_launch(void* const* d_in, const int* in_sizes, int n_in,
                              void* d_out, int out_size, void* d_ws, size_t ws_size,
                              hipStream_t stream)
{
    const float* u = (const float*)d_in[0];   // (256, 1152, 8)
    const float* W = (const float*)d_in[1];   // (1, 1152, 10, 16, 8)
    float* out = (float*)d_out;               // (256, 10, 16)
    float* ws = (float*)d_ws;

    float* s    = ws;                          // 40960 floats
    float* sq   = ws + 40960;                  // 1 (padded to 64)
    float* ab   = ws + 41024;                  // 2 * 92160
    unsigned short* part = (unsigned short*)(ws + 41024 + 2 * AB_STRIDE);  // 72*40960 bf16 (~5.9MB)

    for (int it = 0; it < 3; ++it) {
        k_s<<<dim3(NSPLIT, YB_S), dim3(256), 0, stream>>>(u, W, ab, part, sq, it);
        k_sq<<<dim3(BATCH * COLS / 64), dim3(256), 0, stream>>>(part, s, sq);
        if (it < 2)
            k_a<<<dim3(R_NODES / 8, YBLK), dim3(256), 0, stream>>>(u, W, s, sq,
                                                                   ab + (size_t)it * AB_STRIDE);
        else
            k_scale<<<dim3(BATCH * COLS / 256), dim3(256), 0, stream>>>(s, sq, out);
    }
}